// Round 3
// baseline (2341.325 us; speedup 1.0000x reference)
//
#include <hip/hip_runtime.h>

typedef unsigned int u32;
typedef unsigned short u16;
typedef short s16x8 __attribute__((ext_vector_type(8)));
typedef float f32x4 __attribute__((ext_vector_type(4)));

#define BETA_MIN 0.1f
#define BETA_MAX 20.0f

#define MFMA16(a, b, c) __builtin_amdgcn_mfma_f32_16x16x32_bf16(a, b, c, 0, 0, 0)

__device__ __forceinline__ u16 f2bf(float f) {
    u32 u = __float_as_uint(f);
    u32 r = u + 0x7FFFu + ((u >> 16) & 1u);   // round-to-nearest-even on bf16 boundary
    return (u16)(r >> 16);
}
__device__ __forceinline__ float bf2f(u16 h) {
    return __uint_as_float(((u32)h) << 16);
}
__device__ __forceinline__ f32x4 zero4() {
    f32x4 z = {0.f, 0.f, 0.f, 0.f};
    return z;
}
// pack 2 fp32 -> 2 bf16 (RNE) in one VALU op
__device__ __forceinline__ u32 cvtpk_bf16(float a, float b) {
    u32 r;
    asm("v_cvt_pk_bf16_f32 %0, %1, %2" : "=v"(r) : "v"(a), "v"(b));
    return r;
}

// DPP lane-rotate within 16-lane rows; VALU-latency cross-lane (vs ds_swizzle ~100cyc)
template <int CTRL>
__device__ __forceinline__ float dppf(float x) {
    return __int_as_float(__builtin_amdgcn_update_dpp(
        0, __float_as_int(x), CTRL, 0xF, 0xF, false));
}
// reduce across the 16 contiguous lanes of a DPP row; all lanes get the result
__device__ __forceinline__ float rowmax16(float x) {
    x = fmaxf(x, dppf<0xB1>(x));    // quad_perm [1,0,3,2]  (xor 1)
    x = fmaxf(x, dppf<0x4E>(x));    // quad_perm [2,3,0,1]  (xor 2)
    x = fmaxf(x, dppf<0x124>(x));   // row_ror:4
    x = fmaxf(x, dppf<0x128>(x));   // row_ror:8
    return x;
}
__device__ __forceinline__ float rowsum16(float x) {
    x += dppf<0xB1>(x);
    x += dppf<0x4E>(x);
    x += dppf<0x124>(x);
    x += dppf<0x128>(x);
    return x;
}

// ---------------------------------------------------------------- prep kernels

// Per-row VP-SDE constants: rowc[n] = {a = mean*inv_var, b = -0.5*mean^2*inv_var, inv_var, 0}
__global__ void rows_kernel(const float* __restrict__ t, float* __restrict__ rowc, int N) {
    int n = blockIdx.x * blockDim.x + threadIdx.x;
    if (n >= N) return;
    float tv   = t[n];
    float lm   = -0.25f * tv * tv * (BETA_MAX - BETA_MIN) - 0.5f * tv * BETA_MIN;
    float mean = __expf(lm);
    float e2   = __expf(2.0f * lm);
    float s2   = fmaxf(1.0f - e2, 1e-12f);
    float iv   = 1.0f / s2;
    rowc[n * 4 + 0] = mean * iv;
    rowc[n * 4 + 1] = -0.5f * mean * mean * iv;
    rowc[n * 4 + 2] = iv;
    rowc[n * 4 + 3] = 0.f;
}

// fp32 -> (hi bf16, lo bf16 of residual), vectorized float4
__global__ void conv_hilo(const float* __restrict__ src, u16* __restrict__ hi,
                          u16* __restrict__ lo, int total4) {
    int idx = blockIdx.x * blockDim.x + threadIdx.x;
    if (idx >= total4) return;
    float4 v = ((const float4*)src)[idx];
    float f[4] = {v.x, v.y, v.z, v.w};
    u32 hp[2], lp[2];
    u16 h[4], l[4];
#pragma unroll
    for (int j = 0; j < 4; ++j) {
        h[j] = f2bf(f[j]);
        l[j] = f2bf(f[j] - bf2f(h[j]));
    }
    hp[0] = (u32)h[0] | ((u32)h[1] << 16);
    hp[1] = (u32)h[2] | ((u32)h[3] << 16);
    lp[0] = (u32)l[0] | ((u32)l[1] << 16);
    lp[1] = (u32)l[2] | ((u32)l[3] << 16);
    ((uint2*)hi)[idx] = make_uint2(hp[0], hp[1]);
    ((uint2*)lo)[idx] = make_uint2(lp[0], lp[1]);
}

// Vt[d][m] = bf16(train[m][d]); y2[m] = ||y_m||^2.
// LDS-transposed so Vt stores are 16B coalesced (old version: 2B scatter @ 32KB stride).
__global__ __launch_bounds__(256)
void vt_y2_kernel(const float* __restrict__ train, u16* __restrict__ Vt,
                  float* __restrict__ y2, int M) {
    __shared__ u16 T[128][66];
    const int t = threadIdx.x;
    const int m0 = blockIdx.x * 64;
    const int g = t >> 5, ln = t & 31;
#pragma unroll
    for (int i = 0; i < 8; ++i) {
        int lr = i * 8 + g;
        const float* row = train + (size_t)(m0 + lr) * 128;
        float acc = 0.f;
#pragma unroll
        for (int j = 0; j < 4; ++j) {
            float v = row[ln + 32 * j];          // coalesced: lanes 0..31 -> 128B line
            T[ln + 32 * j][lr] = f2bf(v);        // conflict-free transpose write
            acc += v * v;
        }
#pragma unroll
        for (int d = 16; d >= 1; d >>= 1) acc += __shfl_xor(acc, d, 32);
        if (ln == 0) y2[m0 + lr] = acc;
    }
    __syncthreads();
#pragma unroll
    for (int i = 0; i < 4; ++i) {
        int c = i * 256 + t;                     // 0..1023
        int d = c >> 3, mo = (c & 7) * 8;
        u32 w0 = *(const u32*)&T[d][mo + 0];
        u32 w1 = *(const u32*)&T[d][mo + 2];
        u32 w2 = *(const u32*)&T[d][mo + 4];
        u32 w3 = *(const u32*)&T[d][mo + 6];
        *(uint4*)(Vt + (size_t)d * M + m0 + mo) = make_uint4(w0, w1, w2, w3);
    }
}

// ---------------------------------------------------------------- flash kernel
// grid = (N/64, split); block = 256 (4 waves, 16 q-rows/wave); K-tile = 32 points.
// S = a_n * (Qhi*Khi + Qlo*Khi + Qhi*Klo) + b_n * y2[m]  (bf16x3 split precision)
// LDS = exactly 32 KB.
// __launch_bounds__(256, 3): r0-r2 showed the (256,4) tier caps the UNIFIED
// VGPR+AGPR budget at 128/wave; steady state is ~96-100, so any extra live state
// (r1: 24 staging regs; r2: s[4] arrays across a branch) spilled to scratch
// (WRITE_SIZE 33->851/65 MB). 3 waves/EU -> 170-reg cap; measured occupancy was
// only ~13 waves/CU anyway, so 12 costs ~nothing and buys headroom for:
// T14 async-stage: next tile's global loads issue right after barrier B, land in
//   registers during this tile's ~600cy compute; ds_write after the next barrier A.
// T13 defer-max (per-k scalar form, 2-reg live range): skip rowmax/alpha/O-rescale
//   unless some score exceeds m_run+8 (P bounded by e^8; math exact).
__global__ __launch_bounds__(256, 3)
void flash_kernel(const u16* __restrict__ Khi, const u16* __restrict__ Klo,
                  const u16* __restrict__ Vt,  const u16* __restrict__ Qhi,
                  const u16* __restrict__ Qlo, const float* __restrict__ rowc,
                  const float* __restrict__ y2, float* __restrict__ partO,
                  float* __restrict__ partML, int N, int M, int mchunk) {
    __shared__ u16 sKhi[32][136];      // +8 pad: 16B-aligned rows
    __shared__ u16 sKlo[32][136];
    __shared__ u16 sVt[128][40];       // V transposed: [d][m], pad 32->40
    __shared__ u16 sP[4][16][40];      // per-wave P tile (C-layout -> A-layout)

    const int tid  = threadIdx.x;
    const int wave = tid >> 6, lane = tid & 63;
    const int l15  = lane & 15, quad = lane >> 4;
    const int qb = blockIdx.x, chunk = blockIdx.y;
    const int q0 = qb * 64 + wave * 16;
    const int m_begin = chunk * mchunk;

    // Q fragments in registers: A-layout A[m=l15][k=quad*8+j]
    s16x8 qh[4], ql[4];
    {
        int row = q0 + l15;
        const u16* ph = Qhi + (size_t)row * 128;
        const u16* pl = Qlo + (size_t)row * 128;
#pragma unroll
        for (int kb = 0; kb < 4; ++kb) {
            qh[kb] = *(const s16x8*)(ph + kb * 32 + quad * 8);
            ql[kb] = *(const s16x8*)(pl + kb * 32 + quad * 8);
        }
    }
    float av[4], bv[4];
#pragma unroll
    for (int k = 0; k < 4; ++k) {
        int r = q0 + quad * 4 + k;
        av[k] = rowc[r * 4 + 0];
        bv[k] = rowc[r * 4 + 1];
    }

    f32x4 O[8];
#pragma unroll
    for (int db = 0; db < 8; ++db) O[db] = zero4();
    float m_run[4], l_run[4];
#pragma unroll
    for (int k = 0; k < 4; ++k) { m_run[k] = -INFINITY; l_run[k] = 0.f; }

    // fixed per-thread staging coords (cover the tile in 2 halves each)
    const int srow = tid >> 4, scol = (tid & 15) * 8;     // K rows 0-15 (+16)
    const int sdd  = tid >> 2, smc  = (tid & 3) * 8;      // Vt dd 0-63 (+64)
    const u16* gKh = Khi + (size_t)(m_begin + srow) * 128 + scol;
    const u16* gKl = Klo + (size_t)(m_begin + srow) * 128 + scol;
    const u16* gVt = Vt  + (size_t)sdd * M + m_begin + smc;
    const float* gy2 = y2 + m_begin + l15;

    // prologue: prefetch tile 0 into registers
    uint4 Lh0 = *(const uint4*)gKh, Lh1 = *(const uint4*)(gKh + 16 * 128);
    uint4 Ll0 = *(const uint4*)gKl, Ll1 = *(const uint4*)(gKl + 16 * 128);
    uint4 Lv0 = *(const uint4*)gVt, Lv1 = *(const uint4*)(gVt + (size_t)64 * M);
    float y2c0 = gy2[0], y2c1 = gy2[16];
    float y2n0 = 0.f, y2n1 = 0.f;

    for (int mt = 0; mt < mchunk; mt += 32) {
        __syncthreads();                       // all waves done reading previous tile
        *(uint4*)&sKhi[srow][scol]      = Lh0;
        *(uint4*)&sKhi[srow + 16][scol] = Lh1;
        *(uint4*)&sKlo[srow][scol]      = Ll0;
        *(uint4*)&sKlo[srow + 16][scol] = Ll1;
        *(uint4*)&sVt[sdd][smc]         = Lv0;
        *(uint4*)&sVt[sdd + 64][smc]    = Lv1;
        __syncthreads();                       // tile visible to all waves

        // issue next tile's loads NOW; HBM/L2 latency hides under this tile's compute
        gKh += 32 * 128; gKl += 32 * 128; gVt += 32; gy2 += 32;
        if (mt + 32 < mchunk) {
            Lh0 = *(const uint4*)gKh; Lh1 = *(const uint4*)(gKh + 16 * 128);
            Ll0 = *(const uint4*)gKl; Ll1 = *(const uint4*)(gKl + 16 * 128);
            Lv0 = *(const uint4*)gVt; Lv1 = *(const uint4*)(gVt + (size_t)64 * M);
            y2n0 = gy2[0]; y2n1 = gy2[16];
        }

        // S GEMM: bf16x3
        f32x4 S0 = zero4(), S1 = zero4();
#pragma unroll
        for (int kb = 0; kb < 4; ++kb) {
            s16x8 bh0 = *(const s16x8*)&sKhi[l15][kb * 32 + quad * 8];
            s16x8 bh1 = *(const s16x8*)&sKhi[16 + l15][kb * 32 + quad * 8];
            s16x8 bl0 = *(const s16x8*)&sKlo[l15][kb * 32 + quad * 8];
            s16x8 bl1 = *(const s16x8*)&sKlo[16 + l15][kb * 32 + quad * 8];
            S0 = MFMA16(qh[kb], bh0, S0);
            S0 = MFMA16(ql[kb], bh0, S0);
            S0 = MFMA16(qh[kb], bl0, S0);
            S1 = MFMA16(qh[kb], bh1, S1);
            S1 = MFMA16(ql[kb], bh1, S1);
            S1 = MFMA16(qh[kb], bl1, S1);
        }

        // online softmax; per-k wave-uniform defer-max branch (no arrays -> no
        // live state across the decision beyond the two scalars s0,s1)
#pragma unroll
        for (int k = 0; k < 4; ++k) {
            float s0 = fmaf(av[k], S0[k], bv[k] * y2c0);
            float s1 = fmaf(av[k], S1[k], bv[k] * y2c1);
            float mx = fmaxf(s0, s1);
            if (__any(mx > m_run[k] + 8.0f)) {
                // slow path: proper rowmax + rescale (first tile always lands here)
                float rm    = rowmax16(mx);
                float mnew  = fmaxf(m_run[k], rm);
                float alpha = __expf(m_run[k] - mnew);   // exp(-inf)=0 on first tile
                float p0 = __expf(s0 - mnew);
                float p1 = __expf(s1 - mnew);
                m_run[k] = mnew;
                l_run[k] = l_run[k] * alpha + (p0 + p1);
                u32 pk = cvtpk_bf16(p0, p1);
                sP[wave][quad * 4 + k][l15]      = (u16)pk;
                sP[wave][quad * 4 + k][16 + l15] = (u16)(pk >> 16);
#pragma unroll
                for (int db = 0; db < 8; ++db) O[db][k] *= alpha;
            } else {
                // fast path: keep m_run; P bounded by e^8; no rowmax, no rescale
                float p0 = __expf(s0 - m_run[k]);
                float p1 = __expf(s1 - m_run[k]);
                l_run[k] += p0 + p1;
                u32 pk = cvtpk_bf16(p0, p1);
                sP[wave][quad * 4 + k][l15]      = (u16)pk;
                sP[wave][quad * 4 + k][16 + l15] = (u16)(pk >> 16);
            }
        }
        // same-wave LDS write->read ordering (per-wave sP region, no barrier needed)
        asm volatile("s_waitcnt lgkmcnt(0)" ::: "memory");

        // PV: A = P (A-layout), B = Vt (B[k=m][n=d])
        s16x8 pa = *(const s16x8*)&sP[wave][l15][quad * 8];
#pragma unroll
        for (int db = 0; db < 8; ++db) {
            s16x8 vb = *(const s16x8*)&sVt[db * 16 + l15][quad * 8];
            O[db] = MFMA16(pa, vb, O[db]);
        }
        y2c0 = y2n0; y2c1 = y2n1;
    }

    // epilogue: unnormalized O + (m, l) partials
#pragma unroll
    for (int db = 0; db < 8; ++db) {
#pragma unroll
        for (int k = 0; k < 4; ++k) {
            int row = q0 + quad * 4 + k;
            partO[((size_t)chunk * N + row) * 128 + db * 16 + l15] = O[db][k];
        }
    }
#pragma unroll
    for (int k = 0; k < 4; ++k) {
        float lsum = rowsum16(l_run[k]);
        if (l15 == 0) {
            int row = q0 + quad * 4 + k;
            partML[((size_t)chunk * N + row) * 2 + 0] = m_run[k];
            partML[((size_t)chunk * N + row) * 2 + 1] = lsum;
        }
    }
}

// ---------------------------------------------------------------- combine
__global__ void combine_kernel(const float* __restrict__ partO, const float* __restrict__ partML,
                               const float* __restrict__ x, const float* __restrict__ rowc,
                               float* __restrict__ out, int N, int split) {
    int n = blockIdx.x, d = threadIdx.x;
    float Mx = -INFINITY;
    for (int c = 0; c < split; ++c)
        Mx = fmaxf(Mx, partML[((size_t)c * N + n) * 2]);
    float L = 0.f, acc = 0.f;
    for (int c = 0; c < split; ++c) {
        float w = __expf(partML[((size_t)c * N + n) * 2] - Mx);
        L   += w * partML[((size_t)c * N + n) * 2 + 1];
        acc += w * partO[((size_t)c * N + n) * 128 + d];
    }
    float evals = acc / L;
    if (evals != evals) evals = 0.f;   // match reference's isnan guard
    float iv = rowc[n * 4 + 2];
    out[(size_t)n * 128 + d] = (evals - x[(size_t)n * 128 + d]) * iv;
}

// ---------------------------------------------------------------- launch
extern "C" void kernel_launch(void* const* d_in, const int* in_sizes, int n_in,
                              void* d_out, int out_size, void* d_ws, size_t ws_size,
                              hipStream_t stream) {
    const float* x     = (const float*)d_in[0];
    const float* t     = (const float*)d_in[1];
    const float* train = (const float*)d_in[2];
    float* out = (float*)d_out;

    const int N = in_sizes[1];            // 4096
    const int D = 128;
    const int M = in_sizes[2] / D;        // 16384

    char* ws = (char*)d_ws;
    size_t off = 0;
    auto alloc = [&](size_t bytes) -> void* {
        void* p = ws + off;
        off = (off + bytes + 255) & ~(size_t)255;
        return p;
    };
    u16* Khi   = (u16*)alloc((size_t)M * D * 2);
    u16* Klo   = (u16*)alloc((size_t)M * D * 2);
    u16* Vt    = (u16*)alloc((size_t)M * D * 2);
    u16* Qhi   = (u16*)alloc((size_t)N * D * 2);
    u16* Qlo   = (u16*)alloc((size_t)N * D * 2);
    float* rowc = (float*)alloc((size_t)N * 16);
    float* y2   = (float*)alloc((size_t)M * 4);
    size_t base = off;
    size_t per  = (size_t)N * D * 4 + (size_t)N * 8 + 512;   // partO + partML per chunk
    int split = 16;
    while (split > 1 && base + per * split > ws_size) split >>= 1;
    float* partO  = (float*)alloc((size_t)split * N * D * 4);
    float* partML = (float*)alloc((size_t)split * N * 8);

    rows_kernel<<<(N + 255) / 256, 256, 0, stream>>>(t, rowc, N);
    conv_hilo<<<(N * D / 4 + 255) / 256, 256, 0, stream>>>(x, Qhi, Qlo, N * D / 4);
    conv_hilo<<<(M * D / 4 + 255) / 256, 256, 0, stream>>>(train, Khi, Klo, M * D / 4);
    vt_y2_kernel<<<M / 64, 256, 0, stream>>>(train, Vt, y2, M);

    int mchunk = M / split;
    dim3 grid(N / 64, split);
    flash_kernel<<<grid, 256, 0, stream>>>(Khi, Klo, Vt, Qhi, Qlo, rowc, y2,
                                           partO, partML, N, M, mchunk);
    combine_kernel<<<N, 128, 0, stream>>>(partO, partML, x, rowc, out, N, split);
}

// Round 4
// 202.165 us; speedup vs baseline: 11.5813x; 11.5813x over previous
//
#include <hip/hip_runtime.h>

typedef unsigned int u32;
typedef unsigned short u16;
typedef short s16x8 __attribute__((ext_vector_type(8)));
typedef float f32x4 __attribute__((ext_vector_type(4)));

#define BETA_MIN 0.1f
#define BETA_MAX 20.0f

#define MFMA16(a, b, c) __builtin_amdgcn_mfma_f32_16x16x32_bf16(a, b, c, 0, 0, 0)

__device__ __forceinline__ u16 f2bf(float f) {
    u32 u = __float_as_uint(f);
    u32 r = u + 0x7FFFu + ((u >> 16) & 1u);   // round-to-nearest-even on bf16 boundary
    return (u16)(r >> 16);
}
__device__ __forceinline__ float bf2f(u16 h) {
    return __uint_as_float(((u32)h) << 16);
}
__device__ __forceinline__ f32x4 zero4() {
    f32x4 z = {0.f, 0.f, 0.f, 0.f};
    return z;
}

// DPP lane-rotate within 16-lane rows; VALU-latency cross-lane (vs ds_swizzle ~100cyc)
template <int CTRL>
__device__ __forceinline__ float dppf(float x) {
    return __int_as_float(__builtin_amdgcn_update_dpp(
        0, __float_as_int(x), CTRL, 0xF, 0xF, false));
}
// reduce across the 16 contiguous lanes of a DPP row; all lanes get the result
__device__ __forceinline__ float rowmax16(float x) {
    x = fmaxf(x, dppf<0xB1>(x));    // quad_perm [1,0,3,2]  (xor 1)
    x = fmaxf(x, dppf<0x4E>(x));    // quad_perm [2,3,0,1]  (xor 2)
    x = fmaxf(x, dppf<0x124>(x));   // row_ror:4
    x = fmaxf(x, dppf<0x128>(x));   // row_ror:8
    return x;
}
__device__ __forceinline__ float rowsum16(float x) {
    x += dppf<0xB1>(x);
    x += dppf<0x4E>(x);
    x += dppf<0x124>(x);
    x += dppf<0x128>(x);
    return x;
}

// ---------------------------------------------------------------- prep kernels

// Per-row VP-SDE constants: rowc[n] = {a = mean*inv_var, b = -0.5*mean^2*inv_var, inv_var, 0}
__global__ void rows_kernel(const float* __restrict__ t, float* __restrict__ rowc, int N) {
    int n = blockIdx.x * blockDim.x + threadIdx.x;
    if (n >= N) return;
    float tv   = t[n];
    float lm   = -0.25f * tv * tv * (BETA_MAX - BETA_MIN) - 0.5f * tv * BETA_MIN;
    float mean = __expf(lm);
    float e2   = __expf(2.0f * lm);
    float s2   = fmaxf(1.0f - e2, 1e-12f);
    float iv   = 1.0f / s2;
    rowc[n * 4 + 0] = mean * iv;
    rowc[n * 4 + 1] = -0.5f * mean * mean * iv;
    rowc[n * 4 + 2] = iv;
    rowc[n * 4 + 3] = 0.f;
}

// fp32 -> (hi bf16, lo bf16 of residual), vectorized float4
__global__ void conv_hilo(const float* __restrict__ src, u16* __restrict__ hi,
                          u16* __restrict__ lo, int total4) {
    int idx = blockIdx.x * blockDim.x + threadIdx.x;
    if (idx >= total4) return;
    float4 v = ((const float4*)src)[idx];
    float f[4] = {v.x, v.y, v.z, v.w};
    u32 hp[2], lp[2];
    u16 h[4], l[4];
#pragma unroll
    for (int j = 0; j < 4; ++j) {
        h[j] = f2bf(f[j]);
        l[j] = f2bf(f[j] - bf2f(h[j]));
    }
    hp[0] = (u32)h[0] | ((u32)h[1] << 16);
    hp[1] = (u32)h[2] | ((u32)h[3] << 16);
    lp[0] = (u32)l[0] | ((u32)l[1] << 16);
    lp[1] = (u32)l[2] | ((u32)l[3] << 16);
    ((uint2*)hi)[idx] = make_uint2(hp[0], hp[1]);
    ((uint2*)lo)[idx] = make_uint2(lp[0], lp[1]);
}

// Vt[d][m] = bf16(train[m][d]); y2[m] = ||y_m||^2.
// LDS-transposed so Vt stores are 16B coalesced (old version: 2B scatter @ 32KB stride).
__global__ __launch_bounds__(256)
void vt_y2_kernel(const float* __restrict__ train, u16* __restrict__ Vt,
                  float* __restrict__ y2, int M) {
    __shared__ u16 T[128][66];
    const int t = threadIdx.x;
    const int m0 = blockIdx.x * 64;
    const int g = t >> 5, ln = t & 31;
#pragma unroll
    for (int i = 0; i < 8; ++i) {
        int lr = i * 8 + g;
        const float* row = train + (size_t)(m0 + lr) * 128;
        float acc = 0.f;
#pragma unroll
        for (int j = 0; j < 4; ++j) {
            float v = row[ln + 32 * j];          // coalesced: lanes 0..31 -> 128B line
            T[ln + 32 * j][lr] = f2bf(v);        // conflict-free transpose write
            acc += v * v;
        }
#pragma unroll
        for (int d = 16; d >= 1; d >>= 1) acc += __shfl_xor(acc, d, 32);
        if (ln == 0) y2[m0 + lr] = acc;
    }
    __syncthreads();
#pragma unroll
    for (int i = 0; i < 4; ++i) {
        int c = i * 256 + t;                     // 0..1023
        int d = c >> 3, mo = (c & 7) * 8;
        u32 w0 = *(const u32*)&T[d][mo + 0];
        u32 w1 = *(const u32*)&T[d][mo + 2];
        u32 w2 = *(const u32*)&T[d][mo + 4];
        u32 w3 = *(const u32*)&T[d][mo + 6];
        *(uint4*)(Vt + (size_t)d * M + m0 + mo) = make_uint4(w0, w1, w2, w3);
    }
}

// ---------------------------------------------------------------- flash kernel
// VERBATIM r0 structure (measured 129 us, VGPR 64, zero scratch). r1-r3 proved this
// kernel's regalloc is knife-edge: reg-staging (r1), s[4] arrays across a branch (r2),
// and per-k branches + launch_bounds(256,3) (r3) each tipped the allocator into
// scratch spills (WRITE_SIZE 33MB -> 851MB / 65MB / 6.6GB). Do not add live state
// across the softmax branch; do not change the staging placement.
__global__ __launch_bounds__(256, 4)
void flash_kernel(const u16* __restrict__ Khi, const u16* __restrict__ Klo,
                  const u16* __restrict__ Vt,  const u16* __restrict__ Qhi,
                  const u16* __restrict__ Qlo, const float* __restrict__ rowc,
                  const float* __restrict__ y2, float* __restrict__ partO,
                  float* __restrict__ partML, int N, int M, int mchunk) {
    __shared__ u16 sKhi[32][136];      // +8 pad: 16B-aligned rows
    __shared__ u16 sKlo[32][136];
    __shared__ u16 sVt[128][40];       // V transposed: [d][m], pad 32->40
    __shared__ u16 sP[4][16][40];      // per-wave P tile (C-layout -> A-layout)

    const int tid  = threadIdx.x;
    const int wave = tid >> 6, lane = tid & 63;
    const int l15  = lane & 15, quad = lane >> 4;
    const int qb = blockIdx.x, chunk = blockIdx.y;
    const int q0 = qb * 64 + wave * 16;
    const int m_begin = chunk * mchunk;

    // Q fragments in registers: A-layout A[m=l15][k=quad*8+j]
    s16x8 qh[4], ql[4];
    {
        int row = q0 + l15;
        const u16* ph = Qhi + (size_t)row * 128;
        const u16* pl = Qlo + (size_t)row * 128;
#pragma unroll
        for (int kb = 0; kb < 4; ++kb) {
            qh[kb] = *(const s16x8*)(ph + kb * 32 + quad * 8);
            ql[kb] = *(const s16x8*)(pl + kb * 32 + quad * 8);
        }
    }
    float av[4], bv[4];
#pragma unroll
    for (int k = 0; k < 4; ++k) {
        int r = q0 + quad * 4 + k;
        av[k] = rowc[r * 4 + 0];
        bv[k] = rowc[r * 4 + 1];
    }

    f32x4 O[8];
#pragma unroll
    for (int db = 0; db < 8; ++db) O[db] = zero4();
    float m_run[4], l_run[4];
#pragma unroll
    for (int k = 0; k < 4; ++k) { m_run[k] = -INFINITY; l_run[k] = 0.f; }

    for (int mt = 0; mt < mchunk; mt += 32) {
        const int m0 = m_begin + mt;
        __syncthreads();
        // stage K-tile (hi/lo) + Vt-tile; 512 16B-chunks each, 2 per thread
#pragma unroll
        for (int r = 0; r < 2; ++r) {
            int c = tid + r * 256;
            int row = c >> 4, col = (c & 15) * 8;
            *(uint4*)&sKhi[row][col] = *(const uint4*)(Khi + (size_t)(m0 + row) * 128 + col);
            *(uint4*)&sKlo[row][col] = *(const uint4*)(Klo + (size_t)(m0 + row) * 128 + col);
            int dd = c >> 2, mc = (c & 3) * 8;
            *(uint4*)&sVt[dd][mc] = *(const uint4*)(Vt + (size_t)dd * M + m0 + mc);
        }
        __syncthreads();

        float y2v0 = y2[m0 + l15];
        float y2v1 = y2[m0 + 16 + l15];

        // S GEMM: bf16x3
        f32x4 S[2];
        S[0] = zero4(); S[1] = zero4();
#pragma unroll
        for (int kb = 0; kb < 4; ++kb) {
            s16x8 bh0 = *(const s16x8*)&sKhi[l15][kb * 32 + quad * 8];
            s16x8 bh1 = *(const s16x8*)&sKhi[16 + l15][kb * 32 + quad * 8];
            s16x8 bl0 = *(const s16x8*)&sKlo[l15][kb * 32 + quad * 8];
            s16x8 bl1 = *(const s16x8*)&sKlo[16 + l15][kb * 32 + quad * 8];
            S[0] = MFMA16(qh[kb], bh0, S[0]);
            S[0] = MFMA16(ql[kb], bh0, S[0]);
            S[0] = MFMA16(qh[kb], bl0, S[0]);
            S[1] = MFMA16(qh[kb], bh1, S[1]);
            S[1] = MFMA16(ql[kb], bh1, S[1]);
            S[1] = MFMA16(qh[kb], bl1, S[1]);
        }

        // online softmax; C-layout: row q = quad*4+k (16 contiguous lanes = one DPP row)
#pragma unroll
        for (int k = 0; k < 4; ++k) {
            float s0 = av[k] * S[0][k] + bv[k] * y2v0;
            float s1 = av[k] * S[1][k] + bv[k] * y2v1;
            float rm    = rowmax16(fmaxf(s0, s1));
            float mnew  = fmaxf(m_run[k], rm);
            float alpha = __expf(m_run[k] - mnew);   // exp(-inf)=0 on first tile
            float p0 = __expf(s0 - mnew);
            float p1 = __expf(s1 - mnew);
            m_run[k] = mnew;
            // deferred row-sum: per-lane partial; alpha is row-uniform so this is exact
            l_run[k] = l_run[k] * alpha + (p0 + p1);
            sP[wave][quad * 4 + k][l15]      = f2bf(p0);
            sP[wave][quad * 4 + k][16 + l15] = f2bf(p1);
#pragma unroll
            for (int db = 0; db < 8; ++db) O[db][k] *= alpha;
        }
        // same-wave LDS write->read ordering (per-wave sP region, no barrier needed)
        asm volatile("s_waitcnt lgkmcnt(0)" ::: "memory");

        // PV: A = P (A-layout), B = Vt (B[k=m][n=d])
        s16x8 pa = *(const s16x8*)&sP[wave][l15][quad * 8];
#pragma unroll
        for (int db = 0; db < 8; ++db) {
            s16x8 vb = *(const s16x8*)&sVt[db * 16 + l15][quad * 8];
            O[db] = MFMA16(pa, vb, O[db]);
        }
    }

    // epilogue: unnormalized O + (m, l) partials
#pragma unroll
    for (int db = 0; db < 8; ++db) {
#pragma unroll
        for (int k = 0; k < 4; ++k) {
            int row = q0 + quad * 4 + k;
            partO[((size_t)chunk * N + row) * 128 + db * 16 + l15] = O[db][k];
        }
    }
#pragma unroll
    for (int k = 0; k < 4; ++k) {
        float lsum = rowsum16(l_run[k]);
        if (l15 == 0) {
            int row = q0 + quad * 4 + k;
            partML[((size_t)chunk * N + row) * 2 + 0] = m_run[k];
            partML[((size_t)chunk * N + row) * 2 + 1] = lsum;
        }
    }
}

// ---------------------------------------------------------------- combine
__global__ void combine_kernel(const float* __restrict__ partO, const float* __restrict__ partML,
                               const float* __restrict__ x, const float* __restrict__ rowc,
                               float* __restrict__ out, int N, int split) {
    int n = blockIdx.x, d = threadIdx.x;
    float Mx = -INFINITY;
    for (int c = 0; c < split; ++c)
        Mx = fmaxf(Mx, partML[((size_t)c * N + n) * 2]);
    float L = 0.f, acc = 0.f;
    for (int c = 0; c < split; ++c) {
        float w = __expf(partML[((size_t)c * N + n) * 2] - Mx);
        L   += w * partML[((size_t)c * N + n) * 2 + 1];
        acc += w * partO[((size_t)c * N + n) * 128 + d];
    }
    float evals = acc / L;
    if (evals != evals) evals = 0.f;   // match reference's isnan guard
    float iv = rowc[n * 4 + 2];
    out[(size_t)n * 128 + d] = (evals - x[(size_t)n * 128 + d]) * iv;
}

// ---------------------------------------------------------------- launch
extern "C" void kernel_launch(void* const* d_in, const int* in_sizes, int n_in,
                              void* d_out, int out_size, void* d_ws, size_t ws_size,
                              hipStream_t stream) {
    const float* x     = (const float*)d_in[0];
    const float* t     = (const float*)d_in[1];
    const float* train = (const float*)d_in[2];
    float* out = (float*)d_out;

    const int N = in_sizes[1];            // 4096
    const int D = 128;
    const int M = in_sizes[2] / D;        // 16384

    char* ws = (char*)d_ws;
    size_t off = 0;
    auto alloc = [&](size_t bytes) -> void* {
        void* p = ws + off;
        off = (off + bytes + 255) & ~(size_t)255;
        return p;
    };
    u16* Khi   = (u16*)alloc((size_t)M * D * 2);
    u16* Klo   = (u16*)alloc((size_t)M * D * 2);
    u16* Vt    = (u16*)alloc((size_t)M * D * 2);
    u16* Qhi   = (u16*)alloc((size_t)N * D * 2);
    u16* Qlo   = (u16*)alloc((size_t)N * D * 2);
    float* rowc = (float*)alloc((size_t)N * 16);
    float* y2   = (float*)alloc((size_t)M * 4);
    size_t base = off;
    size_t per  = (size_t)N * D * 4 + (size_t)N * 8 + 512;   // partO + partML per chunk
    int split = 16;
    while (split > 1 && base + per * split > ws_size) split >>= 1;
    float* partO  = (float*)alloc((size_t)split * N * D * 4);
    float* partML = (float*)alloc((size_t)split * N * 8);

    rows_kernel<<<(N + 255) / 256, 256, 0, stream>>>(t, rowc, N);
    conv_hilo<<<(N * D / 4 + 255) / 256, 256, 0, stream>>>(x, Qhi, Qlo, N * D / 4);
    conv_hilo<<<(M * D / 4 + 255) / 256, 256, 0, stream>>>(train, Khi, Klo, M * D / 4);
    vt_y2_kernel<<<M / 64, 256, 0, stream>>>(train, Vt, y2, M);

    int mchunk = M / split;
    dim3 grid(N / 64, split);
    flash_kernel<<<grid, 256, 0, stream>>>(Khi, Klo, Vt, Qhi, Qlo, rowc, y2,
                                           partO, partML, N, M, mchunk);
    combine_kernel<<<N, 128, 0, stream>>>(partO, partML, x, rowc, out, N, split);
}

// Round 5
// 179.010 us; speedup vs baseline: 13.0793x; 1.1293x over previous
//
#include <hip/hip_runtime.h>

typedef unsigned int u32;
typedef unsigned short u16;
typedef short s16x8 __attribute__((ext_vector_type(8)));
typedef float f32x4 __attribute__((ext_vector_type(4)));

#define BETA_MIN 0.1f
#define BETA_MAX 20.0f

#define MFMA16(a, b, c) __builtin_amdgcn_mfma_f32_16x16x32_bf16(a, b, c, 0, 0, 0)

__device__ __forceinline__ u16 f2bf(float f) {
    u32 u = __float_as_uint(f);
    u32 r = u + 0x7FFFu + ((u >> 16) & 1u);   // round-to-nearest-even on bf16 boundary
    return (u16)(r >> 16);
}
__device__ __forceinline__ float bf2f(u16 h) {
    return __uint_as_float(((u32)h) << 16);
}
__device__ __forceinline__ f32x4 zero4() {
    f32x4 z = {0.f, 0.f, 0.f, 0.f};
    return z;
}

// DPP lane-rotate within 16-lane rows; VALU-latency cross-lane (vs ds_swizzle ~100cyc)
template <int CTRL>
__device__ __forceinline__ float dppf(float x) {
    return __int_as_float(__builtin_amdgcn_update_dpp(
        0, __float_as_int(x), CTRL, 0xF, 0xF, false));
}
// reduce across the 16 contiguous lanes of a DPP row; all lanes get the result
__device__ __forceinline__ float rowmax16(float x) {
    x = fmaxf(x, dppf<0xB1>(x));    // quad_perm [1,0,3,2]  (xor 1)
    x = fmaxf(x, dppf<0x4E>(x));    // quad_perm [2,3,0,1]  (xor 2)
    x = fmaxf(x, dppf<0x124>(x));   // row_ror:4
    x = fmaxf(x, dppf<0x128>(x));   // row_ror:8
    return x;
}
__device__ __forceinline__ float rowsum16(float x) {
    x += dppf<0xB1>(x);
    x += dppf<0x4E>(x);
    x += dppf<0x124>(x);
    x += dppf<0x128>(x);
    return x;
}

// ---------------------------------------------------------------- prep kernels

// Fused: fp32 x -> (Qhi, Qlo) bf16x2 split, plus per-row VP-SDE constants.
// rowc[n] = {a = mean*inv_var, b = -0.5*mean^2*inv_var, inv_var, 0}
__global__ void conv_x_rows(const float* __restrict__ src, const float* __restrict__ t,
                            u16* __restrict__ hi, u16* __restrict__ lo,
                            float* __restrict__ rowc, int total4, int N) {
    int idx = blockIdx.x * blockDim.x + threadIdx.x;
    if (idx < N) {
        float tv   = t[idx];
        float lm   = -0.25f * tv * tv * (BETA_MAX - BETA_MIN) - 0.5f * tv * BETA_MIN;
        float mean = __expf(lm);
        float e2   = __expf(2.0f * lm);
        float s2   = fmaxf(1.0f - e2, 1e-12f);
        float iv   = 1.0f / s2;
        rowc[idx * 4 + 0] = mean * iv;
        rowc[idx * 4 + 1] = -0.5f * mean * mean * iv;
        rowc[idx * 4 + 2] = iv;
        rowc[idx * 4 + 3] = 0.f;
    }
    if (idx >= total4) return;
    float4 v = ((const float4*)src)[idx];
    float f[4] = {v.x, v.y, v.z, v.w};
    u32 hp[2], lp[2];
    u16 h[4], l[4];
#pragma unroll
    for (int j = 0; j < 4; ++j) {
        h[j] = f2bf(f[j]);
        l[j] = f2bf(f[j] - bf2f(h[j]));
    }
    hp[0] = (u32)h[0] | ((u32)h[1] << 16);
    hp[1] = (u32)h[2] | ((u32)h[3] << 16);
    lp[0] = (u32)l[0] | ((u32)l[1] << 16);
    lp[1] = (u32)l[2] | ((u32)l[3] << 16);
    ((uint2*)hi)[idx] = make_uint2(hp[0], hp[1]);
    ((uint2*)lo)[idx] = make_uint2(lp[0], lp[1]);
}

// Fused train prep: one pass over train emits Khi/Klo (row-major bf16 hi/lo),
// Vt[d][m] (transposed bf16, via LDS so global stores are 16B coalesced), y2.
__global__ __launch_bounds__(256)
void train_prep_kernel(const float* __restrict__ train, u16* __restrict__ Khi,
                       u16* __restrict__ Klo, u16* __restrict__ Vt,
                       float* __restrict__ y2, int M) {
    __shared__ u16 T[128][66];
    const int t = threadIdx.x;
    const int m0 = blockIdx.x * 64;
    const int g = t >> 5, ln = t & 31;
#pragma unroll
    for (int i = 0; i < 8; ++i) {
        int lr = i * 8 + g;
        int m  = m0 + lr;
        const float* row = train + (size_t)m * 128;
        u16* kh = Khi + (size_t)m * 128;
        u16* kl = Klo + (size_t)m * 128;
        float acc = 0.f;
#pragma unroll
        for (int j = 0; j < 4; ++j) {
            int d = ln + 32 * j;
            float v = row[d];                    // coalesced: lanes 0..31 -> 128B line
            u16 h = f2bf(v);
            u16 l = f2bf(v - bf2f(h));
            T[d][lr] = h;                        // conflict-free transpose write
            kh[d] = h;                           // 32-lane 64B segments
            kl[d] = l;
            acc += v * v;
        }
#pragma unroll
        for (int d = 16; d >= 1; d >>= 1) acc += __shfl_xor(acc, d, 32);
        if (ln == 0) y2[m] = acc;
    }
    __syncthreads();
#pragma unroll
    for (int i = 0; i < 4; ++i) {
        int c = i * 256 + t;                     // 0..1023
        int d = c >> 3, mo = (c & 7) * 8;
        u32 w0 = *(const u32*)&T[d][mo + 0];
        u32 w1 = *(const u32*)&T[d][mo + 2];
        u32 w2 = *(const u32*)&T[d][mo + 4];
        u32 w3 = *(const u32*)&T[d][mo + 6];
        *(uint4*)(Vt + (size_t)d * M + m0 + mo) = make_uint4(w0, w1, w2, w3);
    }
}

// ---------------------------------------------------------------- flash kernel
// grid = (split, N/128); block = 512 (8 waves, 16 q-rows/wave -> 128 q-rows/block).
// Per-wave code is IDENTICAL to the proven 64-VGPR 4-wave shape (r0/r4); r1-r3
// showed regalloc is knife-edge, so scaling is done by adding WAVES, not per-wave
// state. 8 waves amortize each staged K-tile over 2x the q-rows: K-traffic
// 805 MB -> 402 MB (this was the ~6.2 TB/s cache-path bound).
// blockIdx.x = chunk: XCD = linear%8 = chunk%8, so each chunk's 786 KB K-stream
// lives on ONE XCD's L2, shared by its 32 co-resident qb-blocks.
// S = a_n * (Qhi*Khi + Qlo*Khi + Qhi*Klo) + b_n * y2[m]  (bf16x3 split precision)
// LDS = 37.9 KB; 2 blocks/CU resident (grid exactly fills the GPU).
__global__ __launch_bounds__(512, 4)
void flash_kernel(const u16* __restrict__ Khi, const u16* __restrict__ Klo,
                  const u16* __restrict__ Vt,  const u16* __restrict__ Qhi,
                  const u16* __restrict__ Qlo, const float* __restrict__ rowc,
                  const float* __restrict__ y2, float* __restrict__ partO,
                  float* __restrict__ partML, int N, int M, int mchunk) {
    __shared__ u16 sKhi[32][136];      // +8 pad: 16B-aligned rows
    __shared__ u16 sKlo[32][136];
    __shared__ u16 sVt[128][40];       // V transposed: [d][m], pad 32->40
    __shared__ u16 sP[8][16][40];      // per-wave P tile (C-layout -> A-layout)

    const int tid  = threadIdx.x;
    const int wave = tid >> 6, lane = tid & 63;
    const int l15  = lane & 15, quad = lane >> 4;
    const int chunk = blockIdx.x, qb = blockIdx.y;
    const int q0 = qb * 128 + wave * 16;
    const int m_begin = chunk * mchunk;

    // Q fragments in registers: A-layout A[m=l15][k=quad*8+j]
    s16x8 qh[4], ql[4];
    {
        int row = q0 + l15;
        const u16* ph = Qhi + (size_t)row * 128;
        const u16* pl = Qlo + (size_t)row * 128;
#pragma unroll
        for (int kb = 0; kb < 4; ++kb) {
            qh[kb] = *(const s16x8*)(ph + kb * 32 + quad * 8);
            ql[kb] = *(const s16x8*)(pl + kb * 32 + quad * 8);
        }
    }
    float av[4], bv[4];
#pragma unroll
    for (int k = 0; k < 4; ++k) {
        int r = q0 + quad * 4 + k;
        av[k] = rowc[r * 4 + 0];
        bv[k] = rowc[r * 4 + 1];
    }

    f32x4 O[8];
#pragma unroll
    for (int db = 0; db < 8; ++db) O[db] = zero4();
    float m_run[4], l_run[4];
#pragma unroll
    for (int k = 0; k < 4; ++k) { m_run[k] = -INFINITY; l_run[k] = 0.f; }

    for (int mt = 0; mt < mchunk; mt += 32) {
        const int m0 = m_begin + mt;
        __syncthreads();
        // stage K-tile (hi/lo) + Vt-tile; 512 16B-chunks each, 1 per thread
        {
            int row = tid >> 4, col = (tid & 15) * 8;
            *(uint4*)&sKhi[row][col] = *(const uint4*)(Khi + (size_t)(m0 + row) * 128 + col);
            *(uint4*)&sKlo[row][col] = *(const uint4*)(Klo + (size_t)(m0 + row) * 128 + col);
            int dd = tid >> 2, mc = (tid & 3) * 8;
            *(uint4*)&sVt[dd][mc] = *(const uint4*)(Vt + (size_t)dd * M + m0 + mc);
        }
        __syncthreads();

        float y2v0 = y2[m0 + l15];
        float y2v1 = y2[m0 + 16 + l15];

        // S GEMM: bf16x3
        f32x4 S[2];
        S[0] = zero4(); S[1] = zero4();
#pragma unroll
        for (int kb = 0; kb < 4; ++kb) {
            s16x8 bh0 = *(const s16x8*)&sKhi[l15][kb * 32 + quad * 8];
            s16x8 bh1 = *(const s16x8*)&sKhi[16 + l15][kb * 32 + quad * 8];
            s16x8 bl0 = *(const s16x8*)&sKlo[l15][kb * 32 + quad * 8];
            s16x8 bl1 = *(const s16x8*)&sKlo[16 + l15][kb * 32 + quad * 8];
            S[0] = MFMA16(qh[kb], bh0, S[0]);
            S[0] = MFMA16(ql[kb], bh0, S[0]);
            S[0] = MFMA16(qh[kb], bl0, S[0]);
            S[1] = MFMA16(qh[kb], bh1, S[1]);
            S[1] = MFMA16(ql[kb], bh1, S[1]);
            S[1] = MFMA16(qh[kb], bl1, S[1]);
        }

        // online softmax; C-layout: row q = quad*4+k (16 contiguous lanes = one DPP row)
#pragma unroll
        for (int k = 0; k < 4; ++k) {
            float s0 = av[k] * S[0][k] + bv[k] * y2v0;
            float s1 = av[k] * S[1][k] + bv[k] * y2v1;
            float rm    = rowmax16(fmaxf(s0, s1));
            float mnew  = fmaxf(m_run[k], rm);
            float alpha = __expf(m_run[k] - mnew);   // exp(-inf)=0 on first tile
            float p0 = __expf(s0 - mnew);
            float p1 = __expf(s1 - mnew);
            m_run[k] = mnew;
            // deferred row-sum: per-lane partial; alpha is row-uniform so this is exact
            l_run[k] = l_run[k] * alpha + (p0 + p1);
            sP[wave][quad * 4 + k][l15]      = f2bf(p0);
            sP[wave][quad * 4 + k][16 + l15] = f2bf(p1);
#pragma unroll
            for (int db = 0; db < 8; ++db) O[db][k] *= alpha;
        }
        // same-wave LDS write->read ordering (per-wave sP region, no barrier needed)
        asm volatile("s_waitcnt lgkmcnt(0)" ::: "memory");

        // PV: A = P (A-layout), B = Vt (B[k=m][n=d])
        s16x8 pa = *(const s16x8*)&sP[wave][l15][quad * 8];
#pragma unroll
        for (int db = 0; db < 8; ++db) {
            s16x8 vb = *(const s16x8*)&sVt[db * 16 + l15][quad * 8];
            O[db] = MFMA16(pa, vb, O[db]);
        }
    }

    // epilogue: unnormalized O + (m, l) partials
#pragma unroll
    for (int db = 0; db < 8; ++db) {
#pragma unroll
        for (int k = 0; k < 4; ++k) {
            int row = q0 + quad * 4 + k;
            partO[((size_t)chunk * N + row) * 128 + db * 16 + l15] = O[db][k];
        }
    }
#pragma unroll
    for (int k = 0; k < 4; ++k) {
        float lsum = rowsum16(l_run[k]);
        if (l15 == 0) {
            int row = q0 + quad * 4 + k;
            partML[((size_t)chunk * N + row) * 2 + 0] = m_run[k];
            partML[((size_t)chunk * N + row) * 2 + 1] = lsum;
        }
    }
}

// ---------------------------------------------------------------- combine
__global__ void combine_kernel(const float* __restrict__ partO, const float* __restrict__ partML,
                               const float* __restrict__ x, const float* __restrict__ rowc,
                               float* __restrict__ out, int N, int split) {
    int n = blockIdx.x, d = threadIdx.x;
    float Mx = -INFINITY;
    for (int c = 0; c < split; ++c)
        Mx = fmaxf(Mx, partML[((size_t)c * N + n) * 2]);
    float L = 0.f, acc = 0.f;
    for (int c = 0; c < split; ++c) {
        float w = __expf(partML[((size_t)c * N + n) * 2] - Mx);
        L   += w * partML[((size_t)c * N + n) * 2 + 1];
        acc += w * partO[((size_t)c * N + n) * 128 + d];
    }
    float evals = acc / L;
    if (evals != evals) evals = 0.f;   // match reference's isnan guard
    float iv = rowc[n * 4 + 2];
    out[(size_t)n * 128 + d] = (evals - x[(size_t)n * 128 + d]) * iv;
}

// ---------------------------------------------------------------- launch
extern "C" void kernel_launch(void* const* d_in, const int* in_sizes, int n_in,
                              void* d_out, int out_size, void* d_ws, size_t ws_size,
                              hipStream_t stream) {
    const float* x     = (const float*)d_in[0];
    const float* t     = (const float*)d_in[1];
    const float* train = (const float*)d_in[2];
    float* out = (float*)d_out;

    const int N = in_sizes[1];            // 4096
    const int D = 128;
    const int M = in_sizes[2] / D;        // 16384

    char* ws = (char*)d_ws;
    size_t off = 0;
    auto alloc = [&](size_t bytes) -> void* {
        void* p = ws + off;
        off = (off + bytes + 255) & ~(size_t)255;
        return p;
    };
    u16* Khi   = (u16*)alloc((size_t)M * D * 2);
    u16* Klo   = (u16*)alloc((size_t)M * D * 2);
    u16* Vt    = (u16*)alloc((size_t)M * D * 2);
    u16* Qhi   = (u16*)alloc((size_t)N * D * 2);
    u16* Qlo   = (u16*)alloc((size_t)N * D * 2);
    float* rowc = (float*)alloc((size_t)N * 16);
    float* y2   = (float*)alloc((size_t)M * 4);
    size_t base = off;
    size_t per  = (size_t)N * D * 4 + (size_t)N * 8 + 512;   // partO + partML per chunk
    int split = 16;
    while (split > 1 && base + per * split > ws_size) split >>= 1;
    float* partO  = (float*)alloc((size_t)split * N * D * 4);
    float* partML = (float*)alloc((size_t)split * N * 8);

    conv_x_rows<<<(N * D / 4 + 255) / 256, 256, 0, stream>>>(x, t, Qhi, Qlo, rowc,
                                                             N * D / 4, N);
    train_prep_kernel<<<M / 64, 256, 0, stream>>>(train, Khi, Klo, Vt, y2, M);

    int mchunk = M / split;
    dim3 grid(split, N / 128);
    flash_kernel<<<grid, 512, 0, stream>>>(Khi, Klo, Vt, Qhi, Qlo, rowc, y2,
                                           partO, partML, N, M, mchunk);
    combine_kernel<<<N, 128, 0, stream>>>(partO, partML, x, rowc, out, N, split);
}

// Round 6
// 174.208 us; speedup vs baseline: 13.4398x; 1.0276x over previous
//
#include <hip/hip_runtime.h>

typedef unsigned int u32;
typedef unsigned short u16;
typedef short s16x8 __attribute__((ext_vector_type(8)));
typedef float f32x4 __attribute__((ext_vector_type(4)));

#define BETA_MIN 0.1f
#define BETA_MAX 20.0f

#define MFMA16(a, b, c) __builtin_amdgcn_mfma_f32_16x16x32_bf16(a, b, c, 0, 0, 0)

__device__ __forceinline__ u16 f2bf(float f) {
    u32 u = __float_as_uint(f);
    u32 r = u + 0x7FFFu + ((u >> 16) & 1u);   // round-to-nearest-even on bf16 boundary
    return (u16)(r >> 16);
}
__device__ __forceinline__ float bf2f(u16 h) {
    return __uint_as_float(((u32)h) << 16);
}
__device__ __forceinline__ f32x4 zero4() {
    f32x4 z = {0.f, 0.f, 0.f, 0.f};
    return z;
}

// async global->LDS 16B DMA: no VGPR round-trip. Dest = wave-uniform base + lane*16
// (LINEAR), so the bank-swizzle is applied on the per-lane GLOBAL source address and
// again on the LDS read address (both-sides-or-neither, same involution).
__device__ __forceinline__ void gload_lds16(const void* g, void* l) {
    __builtin_amdgcn_global_load_lds(
        (__attribute__((address_space(1))) void*)(void*)g,
        (__attribute__((address_space(3))) void*)l, 16, 0, 0);
}

// DPP lane-rotate within 16-lane rows; VALU-latency cross-lane (vs ds_swizzle ~100cyc)
template <int CTRL>
__device__ __forceinline__ float dppf(float x) {
    return __int_as_float(__builtin_amdgcn_update_dpp(
        0, __float_as_int(x), CTRL, 0xF, 0xF, false));
}
// reduce across the 16 contiguous lanes of a DPP row; all lanes get the result
__device__ __forceinline__ float rowmax16(float x) {
    x = fmaxf(x, dppf<0xB1>(x));    // quad_perm [1,0,3,2]  (xor 1)
    x = fmaxf(x, dppf<0x4E>(x));    // quad_perm [2,3,0,1]  (xor 2)
    x = fmaxf(x, dppf<0x124>(x));   // row_ror:4
    x = fmaxf(x, dppf<0x128>(x));   // row_ror:8
    return x;
}
__device__ __forceinline__ float rowsum16(float x) {
    x += dppf<0xB1>(x);
    x += dppf<0x4E>(x);
    x += dppf<0x124>(x);
    x += dppf<0x128>(x);
    return x;
}

// ---------------------------------------------------------------- fused prep kernel
// blocks [0, nconvblk): x -> Qhi/Qlo bf16x2 split + rowc VP-SDE constants
// blocks [nconvblk, ...): train -> Khi/Klo (row-major) + Vt (LDS-transposed) + y2
__global__ __launch_bounds__(256)
void prep_kernel(const float* __restrict__ x, const float* __restrict__ t,
                 const float* __restrict__ train,
                 u16* __restrict__ Qhi, u16* __restrict__ Qlo, float* __restrict__ rowc,
                 u16* __restrict__ Khi, u16* __restrict__ Klo, u16* __restrict__ Vt,
                 float* __restrict__ y2, int total4, int N, int M, int nconvblk) {
    __shared__ u16 T[128][66];
    if ((int)blockIdx.x < nconvblk) {
        int idx = blockIdx.x * 256 + threadIdx.x;
        if (idx < N) {
            float tv   = t[idx];
            float lm   = -0.25f * tv * tv * (BETA_MAX - BETA_MIN) - 0.5f * tv * BETA_MIN;
            float mean = __expf(lm);
            float e2   = __expf(2.0f * lm);
            float s2   = fmaxf(1.0f - e2, 1e-12f);
            float iv   = 1.0f / s2;
            rowc[idx * 4 + 0] = mean * iv;
            rowc[idx * 4 + 1] = -0.5f * mean * mean * iv;
            rowc[idx * 4 + 2] = iv;
            rowc[idx * 4 + 3] = 0.f;
        }
        if (idx >= total4) return;
        float4 v = ((const float4*)x)[idx];
        float f[4] = {v.x, v.y, v.z, v.w};
        u32 hp[2], lp[2];
        u16 h[4], l[4];
#pragma unroll
        for (int j = 0; j < 4; ++j) {
            h[j] = f2bf(f[j]);
            l[j] = f2bf(f[j] - bf2f(h[j]));
        }
        hp[0] = (u32)h[0] | ((u32)h[1] << 16);
        hp[1] = (u32)h[2] | ((u32)h[3] << 16);
        lp[0] = (u32)l[0] | ((u32)l[1] << 16);
        lp[1] = (u32)l[2] | ((u32)l[3] << 16);
        ((uint2*)Qhi)[idx] = make_uint2(hp[0], hp[1]);
        ((uint2*)Qlo)[idx] = make_uint2(lp[0], lp[1]);
        return;
    }
    // ---- train prep ----
    const int tt = threadIdx.x;
    const int m0 = (blockIdx.x - nconvblk) * 64;
    const int g = tt >> 5, ln = tt & 31;
#pragma unroll
    for (int i = 0; i < 8; ++i) {
        int lr = i * 8 + g;
        int m  = m0 + lr;
        const float* row = train + (size_t)m * 128;
        u16* kh = Khi + (size_t)m * 128;
        u16* kl = Klo + (size_t)m * 128;
        float acc = 0.f;
#pragma unroll
        for (int j = 0; j < 4; ++j) {
            int d = ln + 32 * j;
            float v = row[d];                    // coalesced: lanes 0..31 -> 128B line
            u16 h = f2bf(v);
            u16 l = f2bf(v - bf2f(h));
            T[d][lr] = h;                        // conflict-free transpose write
            kh[d] = h;                           // 32-lane 64B segments
            kl[d] = l;
            acc += v * v;
        }
#pragma unroll
        for (int d = 16; d >= 1; d >>= 1) acc += __shfl_xor(acc, d, 32);
        if (ln == 0) y2[m] = acc;
    }
    __syncthreads();
#pragma unroll
    for (int i = 0; i < 4; ++i) {
        int c = i * 256 + tt;                    // 0..1023
        int d = c >> 3, mo = (c & 7) * 8;
        u32 w0 = *(const u32*)&T[d][mo + 0];
        u32 w1 = *(const u32*)&T[d][mo + 2];
        u32 w2 = *(const u32*)&T[d][mo + 4];
        u32 w3 = *(const u32*)&T[d][mo + 6];
        *(uint4*)(Vt + (size_t)d * M + m0 + mo) = make_uint4(w0, w1, w2, w3);
    }
}

// ---------------------------------------------------------------- flash kernel
// grid = (split, N/128); block = 512 (8 waves, 16 q-rows/wave).
// Per-wave compute is IDENTICAL to the proven 64-VGPR shape (r0/r4/r5) — r1-r3
// showed adding live registers spills; here the ASYNC pipeline is register-free:
// global_load_lds DMA into a double-buffered LDS tile, ONE barrier per tile
// (T3 minimal 2-phase: stage next | compute cur | barrier-drain). The barrier's
// implicit vmcnt(0) drain is the only wait; load latency (~L2, 200-300cy) hides
// under the ~2500cy compute phase.
// Swizzles (both-sides involutions, LDS stays linear for the DMA):
//   K: chunk ^= (row&7)      -> S-reads 2-way (free), 3-bit spread
//   V: chunk ^= ((row>>1)&3) -> PV-reads 2-way (free)
// LDS = 58 KB: sK 2x16KB + sV 2x8KB + sP 10KB -> 2 blocks/CU (= grid residency).
__global__ __launch_bounds__(512, 4)
void flash_kernel(const u16* __restrict__ Khi, const u16* __restrict__ Klo,
                  const u16* __restrict__ Vt,  const u16* __restrict__ Qhi,
                  const u16* __restrict__ Qlo, const float* __restrict__ rowc,
                  const float* __restrict__ y2, float* __restrict__ partO,
                  float* __restrict__ partML, int N, int M, int mchunk) {
    __shared__ u16 sK[2][2][32][128];  // [buf][hi/lo][row][d] LINEAR (DMA dest)
    __shared__ u16 sV[2][128][32];     // [buf][d][m]          LINEAR (DMA dest)
    __shared__ u16 sP[8][16][40];      // per-wave P tile (C-layout -> A-layout)

    const int tid  = threadIdx.x;
    const int wave = tid >> 6, lane = tid & 63;
    const int l15  = lane & 15, quad = lane >> 4;
    const int chunk = blockIdx.x, qb = blockIdx.y;
    const int q0 = qb * 128 + wave * 16;
    const int m_begin = chunk * mchunk;

    // staging source pointers, per-lane, chunk-XOR pre-swizzled to match the reads
    const int kr = tid >> 4;                    // K row 0..31
    const int kc = (tid & 15) ^ (kr & 7);       // source 16B-chunk (involution)
    const int vd = tid >> 2;                    // V d-row 0..127
    const int vc = (tid & 3) ^ ((vd >> 1) & 3);
    const u16* gKh = Khi + (size_t)(m_begin + kr) * 128 + kc * 8;
    const u16* gKl = Klo + (size_t)(m_begin + kr) * 128 + kc * 8;
    const u16* gV  = Vt  + (size_t)vd * M + m_begin + vc * 8;
    const int wb = wave * 1024;                 // wave-uniform byte offset per plane

    // LDS read byte-offsets (hoisted; same XOR as the staged source)
    int aK[4];
#pragma unroll
    for (int kb = 0; kb < 4; ++kb)
        aK[kb] = l15 * 256 + ((((kb * 4 + quad) ^ (l15 & 7))) << 4);
    const int aV = l15 * 64 + ((quad ^ ((l15 >> 1) & 3)) << 4);

    // Q fragments in registers: A-layout A[m=l15][k=quad*8+j]
    s16x8 qh[4], ql[4];
    {
        int row = q0 + l15;
        const u16* ph = Qhi + (size_t)row * 128;
        const u16* pl = Qlo + (size_t)row * 128;
#pragma unroll
        for (int kb = 0; kb < 4; ++kb) {
            qh[kb] = *(const s16x8*)(ph + kb * 32 + quad * 8);
            ql[kb] = *(const s16x8*)(pl + kb * 32 + quad * 8);
        }
    }
    float av[4], bv[4];
#pragma unroll
    for (int k = 0; k < 4; ++k) {
        int r = q0 + quad * 4 + k;
        av[k] = rowc[r * 4 + 0];
        bv[k] = rowc[r * 4 + 1];
    }

    f32x4 O[8];
#pragma unroll
    for (int db = 0; db < 8; ++db) O[db] = zero4();
    float m_run[4], l_run[4];
#pragma unroll
    for (int k = 0; k < 4; ++k) { m_run[k] = -INFINITY; l_run[k] = 0.f; }

    // stage(buf): 3 async 16B DMAs per thread, zero data VGPRs; advances sources
    auto stage = [&](int buf) {
        gload_lds16(gKh, (char*)&sK[buf][0][0][0] + wb);
        gload_lds16(gKl, (char*)&sK[buf][1][0][0] + wb);
        gload_lds16(gV,  (char*)&sV[buf][0][0]    + wb);
        gKh += 32 * 128; gKl += 32 * 128; gV += 32;
    };

    stage(0);
    __syncthreads();                    // implicit vmcnt(0) drain: tile 0 ready
    int cur = 0;

    for (int mt = 0; mt < mchunk; mt += 32) {
        if (mt + 32 < mchunk) stage(cur ^ 1);   // async: lands by next barrier
        const int m0 = m_begin + mt;
        float y2v0 = y2[m0 + l15];
        float y2v1 = y2[m0 + 16 + l15];

        const char* Kb = (const char*)&sK[cur][0][0][0];
        const char* Vb = (const char*)&sV[cur][0][0];

        // S GEMM: bf16x3
        f32x4 S[2];
        S[0] = zero4(); S[1] = zero4();
#pragma unroll
        for (int kb = 0; kb < 4; ++kb) {
            s16x8 bh0 = *(const s16x8*)(Kb + aK[kb]);           // hi, rows l15
            s16x8 bh1 = *(const s16x8*)(Kb + aK[kb] + 4096);    // hi, rows 16+l15
            s16x8 bl0 = *(const s16x8*)(Kb + aK[kb] + 8192);    // lo, rows l15
            s16x8 bl1 = *(const s16x8*)(Kb + aK[kb] + 12288);   // lo, rows 16+l15
            S[0] = MFMA16(qh[kb], bh0, S[0]);
            S[0] = MFMA16(ql[kb], bh0, S[0]);
            S[0] = MFMA16(qh[kb], bl0, S[0]);
            S[1] = MFMA16(qh[kb], bh1, S[1]);
            S[1] = MFMA16(ql[kb], bh1, S[1]);
            S[1] = MFMA16(qh[kb], bl1, S[1]);
        }

        // online softmax; C-layout: row q = quad*4+k (16 contiguous lanes = one DPP row)
#pragma unroll
        for (int k = 0; k < 4; ++k) {
            float s0 = av[k] * S[0][k] + bv[k] * y2v0;
            float s1 = av[k] * S[1][k] + bv[k] * y2v1;
            float rm    = rowmax16(fmaxf(s0, s1));
            float mnew  = fmaxf(m_run[k], rm);
            float alpha = __expf(m_run[k] - mnew);   // exp(-inf)=0 on first tile
            float p0 = __expf(s0 - mnew);
            float p1 = __expf(s1 - mnew);
            m_run[k] = mnew;
            // deferred row-sum: per-lane partial; alpha is row-uniform so this is exact
            l_run[k] = l_run[k] * alpha + (p0 + p1);
            sP[wave][quad * 4 + k][l15]      = f2bf(p0);
            sP[wave][quad * 4 + k][16 + l15] = f2bf(p1);
#pragma unroll
            for (int db = 0; db < 8; ++db) O[db][k] *= alpha;
        }
        // same-wave LDS write->read ordering (per-wave sP region; lgkm only --
        // does NOT stall on the outstanding global_load_lds DMAs, which are vmcnt)
        asm volatile("s_waitcnt lgkmcnt(0)" ::: "memory");

        // PV: A = P (A-layout), B = Vt (B[k=m][n=d])
        s16x8 pa = *(const s16x8*)&sP[wave][l15][quad * 8];
#pragma unroll
        for (int db = 0; db < 8; ++db) {
            s16x8 vb = *(const s16x8*)(Vb + db * 1024 + aV);
            O[db] = MFMA16(pa, vb, O[db]);
        }
        __syncthreads();   // drains vmcnt: next tile's DMAs landed; all reads done
        cur ^= 1;
    }

    // epilogue: unnormalized O + (m, l) partials
#pragma unroll
    for (int db = 0; db < 8; ++db) {
#pragma unroll
        for (int k = 0; k < 4; ++k) {
            int row = q0 + quad * 4 + k;
            partO[((size_t)chunk * N + row) * 128 + db * 16 + l15] = O[db][k];
        }
    }
#pragma unroll
    for (int k = 0; k < 4; ++k) {
        float lsum = rowsum16(l_run[k]);
        if (l15 == 0) {
            int row = q0 + quad * 4 + k;
            partML[((size_t)chunk * N + row) * 2 + 0] = m_run[k];
            partML[((size_t)chunk * N + row) * 2 + 1] = lsum;
        }
    }
}

// ---------------------------------------------------------------- combine
__global__ void combine_kernel(const float* __restrict__ partO, const float* __restrict__ partML,
                               const float* __restrict__ x, const float* __restrict__ rowc,
                               float* __restrict__ out, int N, int split) {
    int n = blockIdx.x, d = threadIdx.x;
    float Mx = -INFINITY;
    for (int c = 0; c < split; ++c)
        Mx = fmaxf(Mx, partML[((size_t)c * N + n) * 2]);
    float L = 0.f, acc = 0.f;
    for (int c = 0; c < split; ++c) {
        float w = __expf(partML[((size_t)c * N + n) * 2] - Mx);
        L   += w * partML[((size_t)c * N + n) * 2 + 1];
        acc += w * partO[((size_t)c * N + n) * 128 + d];
    }
    float evals = acc / L;
    if (evals != evals) evals = 0.f;   // match reference's isnan guard
    float iv = rowc[n * 4 + 2];
    out[(size_t)n * 128 + d] = (evals - x[(size_t)n * 128 + d]) * iv;
}

// ---------------------------------------------------------------- launch
extern "C" void kernel_launch(void* const* d_in, const int* in_sizes, int n_in,
                              void* d_out, int out_size, void* d_ws, size_t ws_size,
                              hipStream_t stream) {
    const float* x     = (const float*)d_in[0];
    const float* t     = (const float*)d_in[1];
    const float* train = (const float*)d_in[2];
    float* out = (float*)d_out;

    const int N = in_sizes[1];            // 4096
    const int D = 128;
    const int M = in_sizes[2] / D;        // 16384

    char* ws = (char*)d_ws;
    size_t off = 0;
    auto alloc = [&](size_t bytes) -> void* {
        void* p = ws + off;
        off = (off + bytes + 255) & ~(size_t)255;
        return p;
    };
    u16* Khi   = (u16*)alloc((size_t)M * D * 2);
    u16* Klo   = (u16*)alloc((size_t)M * D * 2);
    u16* Vt    = (u16*)alloc((size_t)M * D * 2);
    u16* Qhi   = (u16*)alloc((size_t)N * D * 2);
    u16* Qlo   = (u16*)alloc((size_t)N * D * 2);
    float* rowc = (float*)alloc((size_t)N * 16);
    float* y2   = (float*)alloc((size_t)M * 4);
    size_t base = off;
    size_t per  = (size_t)N * D * 4 + (size_t)N * 8 + 512;   // partO + partML per chunk
    int split = 16;
    while (split > 1 && base + per * split > ws_size) split >>= 1;
    float* partO  = (float*)alloc((size_t)split * N * D * 4);
    float* partML = (float*)alloc((size_t)split * N * 8);

    int nconvblk = (N * D / 4 + 255) / 256;          // 512
    int nblk = nconvblk + M / 64;                    // + 256
    prep_kernel<<<nblk, 256, 0, stream>>>(x, t, train, Qhi, Qlo, rowc,
                                          Khi, Klo, Vt, y2, N * D / 4, N, M, nconvblk);

    int mchunk = M / split;
    dim3 grid(split, N / 128);
    flash_kernel<<<grid, 512, 0, stream>>>(Khi, Klo, Vt, Qhi, Qlo, rowc, y2,
                                           partO, partML, N, M, mchunk);
    combine_kernel<<<N, 128, 0, stream>>>(partO, partML, x, rowc, out, N, split);
}